// Round 8
// baseline (146.590 us; speedup 1.0000x reference)
//
#include <hip/hip_runtime.h>
#include <hip/hip_bf16.h>
#include <stdint.h>

#define NQ 10
#define DIMQ 1024
#define NLAYERS 4
#define BATCH 4096
#define NOUT 16

#define GM 4096
#define GN 2048
#define GK 1024

using f32x4 = __attribute__((ext_vector_type(4))) float;
using s16x8 = __attribute__((ext_vector_type(8))) short;

__device__ __forceinline__ float bf2f(unsigned short u) {
  union { unsigned int i; float f; } v; v.i = ((unsigned int)u) << 16; return v.f;
}
__device__ __forceinline__ unsigned short f2bf(float f) {
  union { float f; unsigned int i; } v; v.f = f;
  unsigned int x = v.i;
  return (unsigned short)((x + 0x7fffu + ((x >> 16) & 1u)) >> 16);  // RNE, finite inputs
}

// -------------------------------------------- prep: normalize ∪ build_u ---
// 2048 blocks. Even blocks: normalize 4 rows of X -> Xn (bf16). Odd blocks:
// build one basis column of U (4 waves/column, register state, LDS only for
// the 16 wave-bit exchanges). The two types are independent; fusing them
// lets memory-bound normalize waves backfill build_u's latency stalls and
// drops one kernel launch.
__global__ __launch_bounds__(256) void prep(const float* __restrict__ X,
                                            unsigned short* __restrict__ Xn,
                                            const float* __restrict__ wts,
                                            unsigned int* __restrict__ Ut) {
  __shared__ __align__(16) float buf[2][4][64][12];  // 8 used + 4 pad
  __shared__ float gates[NLAYERS * NQ][8];
  const int type = blockIdx.x & 1;
  const int idx = blockIdx.x >> 1;

  if (type == 0) {
    // ---------------- normalize ----------------
    int lane = threadIdx.x & 63;
    int row = idx * 4 + (threadIdx.x >> 6);
    const float* xr = X + (size_t)row * DIMQ;
    float4 v[4];
    float ss = 0.f;
    #pragma unroll
    for (int ii = 0; ii < 4; ++ii) {
      v[ii] = *(const float4*)(xr + ii * 256 + lane * 4);
      ss += v[ii].x*v[ii].x + v[ii].y*v[ii].y + v[ii].z*v[ii].z + v[ii].w*v[ii].w;
    }
    #pragma unroll
    for (int off = 32; off > 0; off >>= 1) ss += __shfl_xor(ss, off, 64);
    float rn = rsqrtf(ss);
    #pragma unroll
    for (int ii = 0; ii < 4; ++ii) {
      ushort4 o;
      o.x = f2bf(v[ii].x * rn); o.y = f2bf(v[ii].y * rn);
      o.z = f2bf(v[ii].z * rn); o.w = f2bf(v[ii].w * rn);
      *(ushort4*)(Xn + (size_t)row * DIMQ + ii * 256 + lane * 4) = o;
    }
    return;
  }

  // ---------------- build_u: column c = idx ----------------
  const int lane = threadIdx.x & 63;
  const int h = threadIdx.x >> 6;
  const int c = idx;

  if (threadIdx.x < NLAYERS * NQ) {
    int g = threadIdx.x;
    float phi = wts[g * 3 + 0], th = wts[g * 3 + 1], om = wts[g * 3 + 2];
    float ct = cosf(0.5f * th), s = sinf(0.5f * th);
    float ap = 0.5f * (phi + om), am = 0.5f * (phi - om);
    float cp = cosf(ap), spp = sinf(ap), cm = cosf(am), sm = sinf(am);
    float* G = gates[g];
    G[0] = ct * cp;  G[1] = -ct * spp;   // a = e^{-i(phi+om)/2} c
    G[2] = -s * cm;  G[3] = -s * sm;     // b = -e^{+i(phi-om)/2} s
    G[4] = s * cm;   G[5] = -s * sm;     // c = e^{-i(phi-om)/2} s
    G[6] = ct * cp;  G[7] = ct * spp;    // d = e^{+i(phi+om)/2} c
  }
  __syncthreads();

  float sR[4], sI[4], pR[4], pI[4];
  #pragma unroll
  for (int e = 0; e < 4; ++e) {
    sR[e] = (h == (c >> 8) && lane == ((c >> 2) & 63) && e == (c & 3)) ? 1.f : 0.f;
    sI[e] = 0.f;
  }
  int ev = 0;
  auto exchange = [&](int mw) {
    float* wp = &buf[ev & 1][h][lane][0];
    *(float4*)(wp + 0) = make_float4(sR[0], sI[0], sR[1], sI[1]);
    *(float4*)(wp + 4) = make_float4(sR[2], sI[2], sR[3], sI[3]);
    __syncthreads();
    const float* rp = &buf[ev & 1][h ^ mw][lane][0];
    float4 t0 = *(const float4*)(rp + 0);
    float4 t1 = *(const float4*)(rp + 4);
    pR[0] = t0.x; pI[0] = t0.y; pR[1] = t0.z; pI[1] = t0.w;
    pR[2] = t1.x; pI[2] = t1.y; pR[3] = t1.z; pI[3] = t1.w;
    ++ev;
  };

  #pragma unroll
  for (int l = 0; l < NLAYERS; ++l) {
    #pragma unroll
    for (int q = 0; q < NQ; ++q) {
      const float* G = gates[l * NQ + q];
      const float G0 = G[0], G1 = G[1], G2 = G[2], G3 = G[3];
      const float G4 = G[4], G5 = G[5], G6 = G[6], G7 = G[7];
      const int p = 9 - q;                       // qubit q <-> bit p
      if (p < 2) {                               // reg bit
        const int mt = 1 << p;
        #pragma unroll
        for (int e0 = 0; e0 < 4; ++e0) {
          if (e0 & mt) continue;
          const int e1 = e0 | mt;
          float r0 = sR[e0], i0 = sI[e0], r1 = sR[e1], i1 = sI[e1];
          sR[e0] = G0*r0 - G1*i0 + G2*r1 - G3*i1;
          sI[e0] = G0*i0 + G1*r0 + G2*i1 + G3*r1;
          sR[e1] = G4*r0 - G5*i0 + G6*r1 - G7*i1;
          sI[e1] = G4*i0 + G5*r0 + G6*i1 + G7*r1;
        }
      } else if (p < 8) {                        // lane bit
        const int m = 1 << (p - 2);
        const int L = (lane >> (p - 2)) & 1;
        const float aR = L ? G6 : G0, aI = L ? G7 : G1;
        const float bR = L ? G4 : G2, bI = L ? G5 : G3;
        #pragma unroll
        for (int e = 0; e < 4; ++e) {
          float oR = __shfl_xor(sR[e], m, 64);
          float oI = __shfl_xor(sI[e], m, 64);
          float r = sR[e], i = sI[e];
          sR[e] = aR*r - aI*i + bR*oR - bI*oI;
          sI[e] = aR*i + aI*r + bR*oI + bI*oR;
        }
      } else {                                   // wave bit (p=8,9)
        exchange(1 << (p - 8));
        const int L = (h >> (p - 8)) & 1;
        const float aR = L ? G6 : G0, aI = L ? G7 : G1;
        const float bR = L ? G4 : G2, bI = L ? G5 : G3;
        #pragma unroll
        for (int e = 0; e < 4; ++e) {
          float r = sR[e], i = sI[e];
          sR[e] = aR*r - aI*i + bR*pR[e] - bI*pI[e];
          sI[e] = aR*i + aI*r + bR*pI[e] + bI*pR[e];
        }
      }
    }
    const int r = l % (NQ - 1) + 1;
    #pragma unroll
    for (int q = 0; q < NQ; ++q) {
      const int pc = 9 - q, pt = 9 - ((q + r) % NQ);
      if (pt >= 8) {
        exchange(1 << (pt - 8));                 // target = wave bit
        if (pc < 2) {
          #pragma unroll
          for (int e = 0; e < 4; ++e)
            if ((e >> pc) & 1) { sR[e] = pR[e]; sI[e] = pI[e]; }
        } else if (pc < 8) {
          const int ctl = (lane >> (pc - 2)) & 1;
          #pragma unroll
          for (int e = 0; e < 4; ++e) {
            sR[e] = ctl ? pR[e] : sR[e];
            sI[e] = ctl ? pI[e] : sI[e];
          }
        } else {
          if ((h >> (pc - 8)) & 1) {
            #pragma unroll
            for (int e = 0; e < 4; ++e) { sR[e] = pR[e]; sI[e] = pI[e]; }
          }
        }
      } else if (pc >= 8) {                      // wave control, low target
        if (pt < 2) {
          if ((h >> (pc - 8)) & 1) {
            #pragma unroll
            for (int e0 = 0; e0 < 4; ++e0)
              if (((e0 >> pt) & 1) == 0) {
                const int e1 = e0 | (1 << pt);
                float tr = sR[e0]; sR[e0] = sR[e1]; sR[e1] = tr;
                float ti = sI[e0]; sI[e0] = sI[e1]; sI[e1] = ti;
              }
          }
        } else {
          const int m = 1 << (pt - 2);
          const int a = (h >> (pc - 8)) & 1;
          #pragma unroll
          for (int e = 0; e < 4; ++e) {
            float oR = __shfl_xor(sR[e], m, 64);
            float oI = __shfl_xor(sI[e], m, 64);
            if (a) { sR[e] = oR; sI[e] = oI; }
          }
        }
      } else if (pc < 2 && pt < 2) {             // rr
        #pragma unroll
        for (int e = 0; e < 4; ++e)
          if (((e >> pc) & 1) && !((e >> pt) & 1)) {
            const int e2 = e | (1 << pt);
            float tr = sR[e]; sR[e] = sR[e2]; sR[e2] = tr;
            float ti = sI[e]; sI[e] = sI[e2]; sI[e2] = ti;
          }
      } else if (pc >= 2 && pt < 2) {            // lane ctl, reg tgt
        const int ctl = (lane >> (pc - 2)) & 1;
        #pragma unroll
        for (int e0 = 0; e0 < 4; ++e0) {
          if (e0 & (1 << pt)) continue;
          const int e1 = e0 | (1 << pt);
          float r0 = sR[e0], i0 = sI[e0], r1 = sR[e1], i1 = sI[e1];
          sR[e0] = ctl ? r1 : r0;  sI[e0] = ctl ? i1 : i0;
          sR[e1] = ctl ? r0 : r1;  sI[e1] = ctl ? i0 : i1;
        }
      } else if (pc < 2 && pt >= 2) {            // reg ctl, lane tgt
        const int m = 1 << (pt - 2);
        #pragma unroll
        for (int e = 0; e < 4; ++e)
          if ((e >> pc) & 1) {
            sR[e] = __shfl_xor(sR[e], m, 64);
            sI[e] = __shfl_xor(sI[e], m, 64);
          }
      } else {                                   // lane ctl, lane tgt
        const int m = 1 << (pt - 2);
        const int ctl = (lane >> (pc - 2)) & 1;
        #pragma unroll
        for (int e = 0; e < 4; ++e) {
          float oR = __shfl_xor(sR[e], m, 64);
          float oI = __shfl_xor(sI[e], m, 64);
          sR[e] = ctl ? oR : sR[e];
          sI[e] = ctl ? oI : sI[e];
        }
      }
    }
  }

  unsigned int* rowp = Ut + (size_t)c * 1024 + (h << 8) + (lane << 2);
  uint4 o;
  o.x = (unsigned)f2bf(sR[0]) | ((unsigned)f2bf(sI[0]) << 16);
  o.y = (unsigned)f2bf(sR[1]) | ((unsigned)f2bf(sI[1]) << 16);
  o.z = (unsigned)f2bf(sR[2]) | ((unsigned)f2bf(sI[2]) << 16);
  o.w = (unsigned)f2bf(sR[3]) | ((unsigned)f2bf(sI[3]) << 16);
  *(uint4*)rowp = o;
}

// ------------------------------------------------------------- transpose ---
__global__ __launch_bounds__(256) void transpose_u(const unsigned int* __restrict__ Ut,
                                                   unsigned short* __restrict__ Ub) {
  __shared__ unsigned int T[64][65];
  const int t = threadIdx.x;
  const int I0 = (blockIdx.x & 15) * 64;
  const int C0 = (blockIdx.x >> 4) * 64;
  {
    const int cr = t >> 2, ib = (t & 3) * 16;
    const unsigned int* src = Ut + (size_t)(C0 + cr) * 1024 + I0 + ib;
    #pragma unroll
    for (int g4 = 0; g4 < 4; ++g4) {
      uint4 v = *(const uint4*)(src + g4 * 4);
      T[ib + g4*4 + 0][cr] = v.x;
      T[ib + g4*4 + 1][cr] = v.y;
      T[ib + g4*4 + 2][cr] = v.z;
      T[ib + g4*4 + 3][cr] = v.w;
    }
  }
  __syncthreads();
  {
    const int il = t >> 2, cb = (t & 3) * 16;
    union { unsigned short u16[16]; uint4 q[2]; } LO, HI;
    #pragma unroll
    for (int k = 0; k < 16; ++k) {
      unsigned int u = T[il][cb + k];
      LO.u16[k] = (unsigned short)(u & 0xffffu);
      HI.u16[k] = (unsigned short)(u >> 16);
    }
    unsigned short* d0 = Ub + (size_t)(2 * (I0 + il)) * DIMQ + C0 + cb;
    unsigned short* d1 = d0 + DIMQ;
    *(uint4*)(d0 + 0) = LO.q[0];
    *(uint4*)(d0 + 8) = LO.q[1];
    *(uint4*)(d1 + 0) = HI.q[0];
    *(uint4*)(d1 + 8) = HI.q[1];
  }
}

// ----------------------------------------------------- GEMM + z-partials ---
__device__ __forceinline__ void gload_lds16(const void* g, void* lds) {
  __builtin_amdgcn_global_load_lds(
      (const __attribute__((address_space(1))) unsigned int*)g,
      (__attribute__((address_space(3))) unsigned int*)lds, 16, 0, 0);
}

__global__ __launch_bounds__(256, 3) void gemm_bt(const unsigned short* __restrict__ A,
                                                  const unsigned short* __restrict__ B,
                                                  float* __restrict__ Zp) {
  __shared__ char lds[32768];
  char* As = lds;
  char* Bs = lds + 16384;
  int tid = threadIdx.x;
  int lane = tid & 63;
  int w = tid >> 6;
  int mtile = blockIdx.x & 31;
  int ntile = blockIdx.x >> 5;
  int wm = (w & 1) * 64;
  int wn = (w >> 1) * 64;
  const unsigned short* Ag = A + (size_t)mtile * 128 * GK;
  const unsigned short* Bg = B + (size_t)ntile * 128 * GK;
  f32x4 acc[4][4];
  #pragma unroll
  for (int i = 0; i < 4; ++i)
    #pragma unroll
    for (int j = 0; j < 4; ++j) acc[i][j] = (f32x4){0.f, 0.f, 0.f, 0.f};

  for (int kt = 0; kt < GK; kt += 64) {
    __syncthreads();
    #pragma unroll
    for (int s = 0; s < 4; ++s) {
      int chunk = (w << 8) | (s << 6) | lane;
      int row = chunk >> 3, ch = chunk & 7;
      int sch = ch ^ (row & 7);
      gload_lds16(Ag + (size_t)row * GK + kt + sch * 8, As + (((w << 2) + s) << 10));
      gload_lds16(Bg + (size_t)row * GK + kt + sch * 8, Bs + (((w << 2) + s) << 10));
    }
    __builtin_amdgcn_s_waitcnt(0);
    __syncthreads();
    #pragma unroll
    for (int ks = 0; ks < 2; ++ks) {
      s16x8 af[4], bfr[4];
      #pragma unroll
      for (int mt = 0; mt < 4; ++mt) {
        int rowa = wm + mt * 16 + (lane & 15);
        int kc = (ks << 2) + (lane >> 4);
        af[mt] = *(const s16x8*)(As + (((rowa << 3) + (kc ^ (rowa & 7))) << 4));
        int rowb = wn + mt * 16 + (lane & 15);
        bfr[mt] = *(const s16x8*)(Bs + (((rowb << 3) + (kc ^ (rowb & 7))) << 4));
      }
      #pragma unroll
      for (int mt = 0; mt < 4; ++mt)
        #pragma unroll
        for (int nt = 0; nt < 4; ++nt)
          acc[mt][nt] = __builtin_amdgcn_mfma_f32_16x16x32_bf16(af[mt], bfr[nt],
                                                                acc[mt][nt], 0, 0, 0);
    }
  }

  // ---- epilogue: Walsh-Hadamard z-partials (no Y materialization) ----
  const int quad = lane >> 4, cn = lane & 15;
  float* zb = Zp + (size_t)(blockIdx.x * 4 + w) * 6 * 64;
  #pragma unroll
  for (int mt = 0; mt < 4; ++mt) {
    #pragma unroll
    for (int r = 0; r < 4; ++r) {
      float p0 = acc[mt][0][r] * acc[mt][0][r];
      float p1 = acc[mt][1][r] * acc[mt][1][r];
      float p2 = acc[mt][2][r] * acc[mt][2][r];
      float p3 = acc[mt][3][r] * acc[mt][3][r];
      float ca = p0 + p1 + p2 + p3;
      float c3 = p0 - p1 + p2 - p3;              // i bit3 (= nt bit0)
      float c4 = p0 + p1 - p2 - p3;              // i bit4 (= nt bit1)
      #pragma unroll
      for (int m = 1; m <= 8; m <<= 1) {
        float o = __shfl_xor(ca, m, 64);
        ca = (lane & m) ? (o - ca) : (ca + o);   // WHT stage
        c3 += __shfl_xor(c3, m, 64);             // plain sum
        c4 += __shfl_xor(c4, m, 64);
      }
      int rloc = mt * 16 + quad * 4 + r;
      if (cn == 0) {
        zb[5 * 64 + rloc] = ca;                  // W_0: unsigned sum
        zb[3 * 64 + rloc] = c3;
        zb[4 * 64 + rloc] = c4;
      } else if (cn == 2) {
        zb[0 * 64 + rloc] = ca;                  // W_2: i bit0
      } else if (cn == 4) {
        zb[1 * 64 + rloc] = ca;                  // W_4: i bit1
      } else if (cn == 8) {
        zb[2 * 64 + rloc] = ca;                  // W_8: i bit2
      }
    }
  }
}

// -------------------------------------------------------------- finalize ---
__global__ __launch_bounds__(256) void finalize(const float* __restrict__ Zp,
                                                const float* __restrict__ W,
                                                const float* __restrict__ bias,
                                                float* __restrict__ out) {
  int rg = blockIdx.x * 256 + threadIdx.x;      // 0..4095
  int mtile = rg >> 7;
  int rl = rg & 127;
  int wlo = rl >> 6;                            // wave low bit (wm)
  int rloc = rl & 63;
  float z[10];
  #pragma unroll
  for (int q = 0; q < 10; ++q) z[q] = 0.f;
  for (int ntile = 0; ntile < 16; ++ntile) {
    int bid = ntile * 32 + mtile;
    #pragma unroll
    for (int wn = 0; wn < 2; ++wn) {
      int w = (wn << 1) | wlo;
      const float* P = Zp + (size_t)(bid * 4 + w) * 6 * 64 + rloc;
      z[9] += P[0];
      z[8] += P[64];
      z[7] += P[128];
      z[6] += P[192];
      z[5] += P[256];
      float pa = P[320];
      z[4] += wn ? -pa : pa;                    // i bit5
      z[3] += (ntile & 1) ? -pa : pa;           // bit6
      z[2] += (ntile & 2) ? -pa : pa;           // bit7
      z[1] += (ntile & 4) ? -pa : pa;           // bit8
      z[0] += (ntile & 8) ? -pa : pa;           // bit9
    }
  }
  #pragma unroll
  for (int o = 0; o < NOUT; ++o) {
    float a = bias[o];
    #pragma unroll
    for (int q = 0; q < 10; ++q) a += z[q] * W[o * 10 + q];
    out[(size_t)rg * NOUT + o] = a;
  }
}

extern "C" void kernel_launch(void* const* d_in, const int* in_sizes, int n_in,
                              void* d_out, int out_size, void* d_ws, size_t ws_size,
                              hipStream_t stream) {
  const float* X    = (const float*)d_in[0];
  const float* wts  = (const float*)d_in[1];
  const float* W    = (const float*)d_in[2];
  const float* bias = (const float*)d_in[3];
  float* out = (float*)d_out;
  char* ws = (char*)d_ws;
  unsigned short* Xn = (unsigned short*)ws;                       // 8 MB
  unsigned short* Ub = (unsigned short*)(ws + 8u  * 1024 * 1024); // 4 MB
  unsigned int* Ut   = (unsigned int*)(ws + 12u * 1024 * 1024);   // 4 MB
  float* Zp          = (float*)(ws + 16u * 1024 * 1024);          // 3 MB

  hipLaunchKernelGGL(prep,        dim3(2048),      dim3(256), 0, stream, X, Xn, wts, Ut);
  hipLaunchKernelGGL(transpose_u, dim3(256),       dim3(256), 0, stream, Ut, Ub);
  hipLaunchKernelGGL(gemm_bt,     dim3((GM/128)*(GN/128)), dim3(256), 0, stream, Xn, Ub, Zp);
  hipLaunchKernelGGL(finalize,    dim3(BATCH / 256), dim3(256), 0, stream, Zp, W, bias, out);
}

// Round 9
// 130.373 us; speedup vs baseline: 1.1244x; 1.1244x over previous
//
#include <hip/hip_runtime.h>
#include <hip/hip_bf16.h>
#include <stdint.h>

#define NQ 10
#define DIMQ 1024
#define NLAYERS 4
#define BATCH 4096
#define NOUT 16

#define GM 4096
#define GN 2048
#define GK 1024

using f32x4 = __attribute__((ext_vector_type(4))) float;
using s16x8 = __attribute__((ext_vector_type(8))) short;

__device__ __forceinline__ float bf2f(unsigned short u) {
  union { unsigned int i; float f; } v; v.i = ((unsigned int)u) << 16; return v.f;
}
__device__ __forceinline__ unsigned short f2bf(float f) {
  union { float f; unsigned int i; } v; v.f = f;
  unsigned int x = v.i;
  return (unsigned short)((x + 0x7fffu + ((x >> 16) & 1u)) >> 16);  // RNE, finite inputs
}

// broadcast lane i's float to all lanes as a wave-uniform (SGPR) value.
// i must be a compile-time constant; v_readlane = no memory, no latency.
#define RL(v, i) __int_as_float(__builtin_amdgcn_readlane(__float_as_int(v), (i)))

// ------------------------------------------------------------- normalize ---
__global__ __launch_bounds__(256) void normalize_rows(const float* __restrict__ X,
                                                      unsigned short* __restrict__ Xn) {
  int lane = threadIdx.x & 63;
  int row = blockIdx.x * 4 + (threadIdx.x >> 6);
  const float* xr = X + (size_t)row * DIMQ;
  float4 v[4];
  float ss = 0.f;
  #pragma unroll
  for (int ii = 0; ii < 4; ++ii) {
    v[ii] = *(const float4*)(xr + ii * 256 + lane * 4);
    ss += v[ii].x*v[ii].x + v[ii].y*v[ii].y + v[ii].z*v[ii].z + v[ii].w*v[ii].w;
  }
  #pragma unroll
  for (int off = 32; off > 0; off >>= 1) ss += __shfl_xor(ss, off, 64);
  float rn = rsqrtf(ss);
  #pragma unroll
  for (int ii = 0; ii < 4; ++ii) {
    ushort4 o;
    o.x = f2bf(v[ii].x * rn); o.y = f2bf(v[ii].y * rn);
    o.z = f2bf(v[ii].z * rn); o.w = f2bf(v[ii].w * rn);
    *(ushort4*)(Xn + (size_t)row * DIMQ + ii * 256 + lane * 4) = o;
  }
}

// ---------------------------------------------------------------- build U ---
// R5's 2-wave-per-column layout (best measured), with gate coefficients held
// IN REGISTERS: lane g (0..39) computes gate g's 8 coeffs once; each gate
// broadcasts them via v_readlane (compile-time lane index, zero latency).
// No s_load / ds_read inside the 80-gate chain — only the shfl ds_bpermutes.
// i = (h<<9)|(lane<<3)|e : h = wave parity in pair, lane bits 8:3, e bits 2:0.
__global__ __launch_bounds__(256) void build_u(const float* __restrict__ wts,
                                               unsigned int* __restrict__ Ut) {
  __shared__ float buf[2][4][64][20];   // [evbuf][wave][lane][16 used + 4 pad]
  const int lane = threadIdx.x & 63;
  const int w = threadIdx.x >> 6;
  const int h = w & 1;
  const int c = blockIdx.x * 2 + (w >> 1);

  // per-lane gate table: lane g holds gate g's coefficients (g<40)
  float g0, g1, g2, g3, g4, g5, g6, g7;
  {
    const int gi = (lane < NLAYERS * NQ) ? lane : 0;
    float phi = wts[gi * 3 + 0], th = wts[gi * 3 + 1], om = wts[gi * 3 + 2];
    float ct = cosf(0.5f * th), sn = sinf(0.5f * th);
    float ap = 0.5f * (phi + om), am = 0.5f * (phi - om);
    float cp = cosf(ap), spp = sinf(ap), cm = cosf(am), sm = sinf(am);
    g0 = ct * cp;  g1 = -ct * spp;   // a = e^{-i(phi+om)/2} c
    g2 = -sn * cm; g3 = -sn * sm;    // b = -e^{+i(phi-om)/2} s
    g4 = sn * cm;  g5 = -sn * sm;    // c = e^{-i(phi-om)/2} s
    g6 = ct * cp;  g7 = ct * spp;    // d = e^{+i(phi+om)/2} c
  }

  float sR[8], sI[8], pR[8], pI[8];
  #pragma unroll
  for (int e = 0; e < 8; ++e) {
    sR[e] = (h == (c >> 9) && lane == ((c >> 3) & 63) && e == (c & 7)) ? 1.f : 0.f;
    sI[e] = 0.f;
  }
  int ev = 0;
  auto exchange = [&]() {
    float* wp = &buf[ev & 1][w][lane][0];
    #pragma unroll
    for (int g = 0; g < 4; ++g)
      *(float4*)(wp + 4 * g) = make_float4(sR[2*g], sI[2*g], sR[2*g+1], sI[2*g+1]);
    __syncthreads();
    const float* rp = &buf[ev & 1][w ^ 1][lane][0];
    #pragma unroll
    for (int g = 0; g < 4; ++g) {
      float4 t = *(const float4*)(rp + 4 * g);
      pR[2*g] = t.x; pI[2*g] = t.y; pR[2*g+1] = t.z; pI[2*g+1] = t.w;
    }
    ++ev;
  };

  #pragma unroll
  for (int l = 0; l < NLAYERS; ++l) {
    #pragma unroll
    for (int q = 0; q < NQ; ++q) {
      const int gidx = l * NQ + q;
      const float G0 = RL(g0, gidx), G1 = RL(g1, gidx);
      const float G2 = RL(g2, gidx), G3 = RL(g3, gidx);
      const float G4 = RL(g4, gidx), G5 = RL(g5, gidx);
      const float G6 = RL(g6, gidx), G7 = RL(g7, gidx);
      const int p = 9 - q;                       // qubit q <-> bit p
      if (p < 3) {                               // reg bit
        const int mt = 1 << p;
        #pragma unroll
        for (int e0 = 0; e0 < 8; ++e0) {
          if (e0 & mt) continue;
          const int e1 = e0 | mt;
          float r0 = sR[e0], i0 = sI[e0], r1 = sR[e1], i1 = sI[e1];
          sR[e0] = G0*r0 - G1*i0 + G2*r1 - G3*i1;
          sI[e0] = G0*i0 + G1*r0 + G2*i1 + G3*r1;
          sR[e1] = G4*r0 - G5*i0 + G6*r1 - G7*i1;
          sI[e1] = G4*i0 + G5*r0 + G6*i1 + G7*r1;
        }
      } else if (p < 9) {                        // lane bit
        const int m = 1 << (p - 3);
        const int L = (lane >> (p - 3)) & 1;
        const float aR = L ? G6 : G0, aI = L ? G7 : G1;
        const float bR = L ? G4 : G2, bI = L ? G5 : G3;
        #pragma unroll
        for (int e = 0; e < 8; ++e) {
          float oR = __shfl_xor(sR[e], m, 64);
          float oI = __shfl_xor(sI[e], m, 64);
          float r = sR[e], i = sI[e];
          sR[e] = aR*r - aI*i + bR*oR - bI*oI;
          sI[e] = aR*i + aI*r + bR*oI + bI*oR;
        }
      } else {                                   // wave bit (p==9)
        exchange();
        const float aR = h ? G6 : G0, aI = h ? G7 : G1;
        const float bR = h ? G4 : G2, bI = h ? G5 : G3;
        #pragma unroll
        for (int e = 0; e < 8; ++e) {
          float r = sR[e], i = sI[e];
          sR[e] = aR*r - aI*i + bR*pR[e] - bI*pI[e];
          sI[e] = aR*i + aI*r + bR*pI[e] + bI*pR[e];
        }
      }
    }
    const int r = l % (NQ - 1) + 1;
    #pragma unroll
    for (int q = 0; q < NQ; ++q) {
      const int pc = 9 - q, pt = 9 - ((q + r) % NQ);
      if (pt == 9) {                             // target = wave bit: exchange
        exchange();
        if (pc < 3) {
          #pragma unroll
          for (int e = 0; e < 8; ++e)
            if ((e >> pc) & 1) { sR[e] = pR[e]; sI[e] = pI[e]; }
        } else {
          const int ctl = (lane >> (pc - 3)) & 1;
          #pragma unroll
          for (int e = 0; e < 8; ++e) {
            sR[e] = ctl ? pR[e] : sR[e];
            sI[e] = ctl ? pI[e] : sI[e];
          }
        }
      } else if (pc == 9) {                      // control = wave bit (uniform)
        if (pt < 3) {
          if (h) {
            #pragma unroll
            for (int e = 0; e < 8; ++e)
              if (((e >> pt) & 1) == 0) {
                const int e2 = e | (1 << pt);
                float tr = sR[e]; sR[e] = sR[e2]; sR[e2] = tr;
                float ti = sI[e]; sI[e] = sI[e2]; sI[e2] = ti;
              }
          }
        } else {
          const int m = 1 << (pt - 3);
          #pragma unroll
          for (int e = 0; e < 8; ++e) {
            float oR = __shfl_xor(sR[e], m, 64);
            float oI = __shfl_xor(sI[e], m, 64);
            if (h) { sR[e] = oR; sI[e] = oI; }
          }
        }
      } else if (pc < 3 && pt < 3) {
        #pragma unroll
        for (int e = 0; e < 8; ++e)
          if (((e >> pc) & 1) && !((e >> pt) & 1)) {
            const int e2 = e | (1 << pt);
            float tr = sR[e]; sR[e] = sR[e2]; sR[e2] = tr;
            float ti = sI[e]; sI[e] = sI[e2]; sI[e2] = ti;
          }
      } else if (pc >= 3 && pt < 3) {
        const int ctl = (lane >> (pc - 3)) & 1;
        #pragma unroll
        for (int e0 = 0; e0 < 8; ++e0) {
          if (e0 & (1 << pt)) continue;
          const int e1 = e0 | (1 << pt);
          float r0 = sR[e0], i0 = sI[e0], r1 = sR[e1], i1 = sI[e1];
          sR[e0] = ctl ? r1 : r0;  sI[e0] = ctl ? i1 : i0;
          sR[e1] = ctl ? r0 : r1;  sI[e1] = ctl ? i0 : i1;
        }
      } else if (pc < 3 && pt >= 3) {
        const int m = 1 << (pt - 3);
        #pragma unroll
        for (int e = 0; e < 8; ++e)
          if ((e >> pc) & 1) {
            sR[e] = __shfl_xor(sR[e], m, 64);
            sI[e] = __shfl_xor(sI[e], m, 64);
          }
      } else {                                   // both lane bits
        const int m = 1 << (pt - 3);
        const int ctl = (lane >> (pc - 3)) & 1;
        #pragma unroll
        for (int e = 0; e < 8; ++e) {
          float oR = __shfl_xor(sR[e], m, 64);
          float oI = __shfl_xor(sI[e], m, 64);
          sR[e] = ctl ? oR : sR[e];
          sI[e] = ctl ? oI : sI[e];
        }
      }
    }
  }

  // coalesced: Ut[c][i] = pack(bf16 R, bf16 I), i = (h<<9)|(lane<<3)|e
  unsigned int* rowp = Ut + (size_t)c * 1024 + (h << 9) + (lane << 3);
  #pragma unroll
  for (int g4 = 0; g4 < 2; ++g4) {
    uint4 o;
    o.x = (unsigned)f2bf(sR[g4*4+0]) | ((unsigned)f2bf(sI[g4*4+0]) << 16);
    o.y = (unsigned)f2bf(sR[g4*4+1]) | ((unsigned)f2bf(sI[g4*4+1]) << 16);
    o.z = (unsigned)f2bf(sR[g4*4+2]) | ((unsigned)f2bf(sI[g4*4+2]) << 16);
    o.w = (unsigned)f2bf(sR[g4*4+3]) | ((unsigned)f2bf(sI[g4*4+3]) << 16);
    *(uint4*)(rowp + g4 * 4) = o;
  }
}

// ------------------------------------------------------------- transpose ---
__global__ __launch_bounds__(256) void transpose_u(const unsigned int* __restrict__ Ut,
                                                   unsigned short* __restrict__ Ub) {
  __shared__ unsigned int T[64][65];
  const int t = threadIdx.x;
  const int I0 = (blockIdx.x & 15) * 64;
  const int C0 = (blockIdx.x >> 4) * 64;
  {
    const int cr = t >> 2, ib = (t & 3) * 16;
    const unsigned int* src = Ut + (size_t)(C0 + cr) * 1024 + I0 + ib;
    #pragma unroll
    for (int g4 = 0; g4 < 4; ++g4) {
      uint4 v = *(const uint4*)(src + g4 * 4);
      T[ib + g4*4 + 0][cr] = v.x;
      T[ib + g4*4 + 1][cr] = v.y;
      T[ib + g4*4 + 2][cr] = v.z;
      T[ib + g4*4 + 3][cr] = v.w;
    }
  }
  __syncthreads();
  {
    const int il = t >> 2, cb = (t & 3) * 16;
    union { unsigned short u16[16]; uint4 q[2]; } LO, HI;
    #pragma unroll
    for (int k = 0; k < 16; ++k) {
      unsigned int u = T[il][cb + k];
      LO.u16[k] = (unsigned short)(u & 0xffffu);
      HI.u16[k] = (unsigned short)(u >> 16);
    }
    unsigned short* d0 = Ub + (size_t)(2 * (I0 + il)) * DIMQ + C0 + cb;
    unsigned short* d1 = d0 + DIMQ;
    *(uint4*)(d0 + 0) = LO.q[0];
    *(uint4*)(d0 + 8) = LO.q[1];
    *(uint4*)(d1 + 0) = HI.q[0];
    *(uint4*)(d1 + 8) = HI.q[1];
  }
}

// ----------------------------------------------------- GEMM + z-partials ---
__device__ __forceinline__ void gload_lds16(const void* g, void* lds) {
  __builtin_amdgcn_global_load_lds(
      (const __attribute__((address_space(1))) unsigned int*)g,
      (__attribute__((address_space(3))) unsigned int*)lds, 16, 0, 0);
}

__global__ __launch_bounds__(256, 3) void gemm_bt(const unsigned short* __restrict__ A,
                                                  const unsigned short* __restrict__ B,
                                                  float* __restrict__ Zp) {
  __shared__ char lds[32768];
  char* As = lds;
  char* Bs = lds + 16384;
  int tid = threadIdx.x;
  int lane = tid & 63;
  int w = tid >> 6;
  int mtile = blockIdx.x & 31;
  int ntile = blockIdx.x >> 5;
  int wm = (w & 1) * 64;
  int wn = (w >> 1) * 64;
  const unsigned short* Ag = A + (size_t)mtile * 128 * GK;
  const unsigned short* Bg = B + (size_t)ntile * 128 * GK;
  f32x4 acc[4][4];
  #pragma unroll
  for (int i = 0; i < 4; ++i)
    #pragma unroll
    for (int j = 0; j < 4; ++j) acc[i][j] = (f32x4){0.f, 0.f, 0.f, 0.f};

  for (int kt = 0; kt < GK; kt += 64) {
    __syncthreads();
    #pragma unroll
    for (int s = 0; s < 4; ++s) {
      int chunk = (w << 8) | (s << 6) | lane;
      int row = chunk >> 3, ch = chunk & 7;
      int sch = ch ^ (row & 7);
      gload_lds16(Ag + (size_t)row * GK + kt + sch * 8, As + (((w << 2) + s) << 10));
      gload_lds16(Bg + (size_t)row * GK + kt + sch * 8, Bs + (((w << 2) + s) << 10));
    }
    __builtin_amdgcn_s_waitcnt(0);
    __syncthreads();
    #pragma unroll
    for (int ks = 0; ks < 2; ++ks) {
      s16x8 af[4], bfr[4];
      #pragma unroll
      for (int mt = 0; mt < 4; ++mt) {
        int rowa = wm + mt * 16 + (lane & 15);
        int kc = (ks << 2) + (lane >> 4);
        af[mt] = *(const s16x8*)(As + (((rowa << 3) + (kc ^ (rowa & 7))) << 4));
        int rowb = wn + mt * 16 + (lane & 15);
        bfr[mt] = *(const s16x8*)(Bs + (((rowb << 3) + (kc ^ (rowb & 7))) << 4));
      }
      #pragma unroll
      for (int mt = 0; mt < 4; ++mt)
        #pragma unroll
        for (int nt = 0; nt < 4; ++nt)
          acc[mt][nt] = __builtin_amdgcn_mfma_f32_16x16x32_bf16(af[mt], bfr[nt],
                                                                acc[mt][nt], 0, 0, 0);
    }
  }

  // ---- epilogue: Walsh-Hadamard z-partials (no Y materialization) ----
  const int quad = lane >> 4, cn = lane & 15;
  float* zb = Zp + (size_t)(blockIdx.x * 4 + w) * 6 * 64;
  #pragma unroll
  for (int mt = 0; mt < 4; ++mt) {
    #pragma unroll
    for (int r = 0; r < 4; ++r) {
      float p0 = acc[mt][0][r] * acc[mt][0][r];
      float p1 = acc[mt][1][r] * acc[mt][1][r];
      float p2 = acc[mt][2][r] * acc[mt][2][r];
      float p3 = acc[mt][3][r] * acc[mt][3][r];
      float ca = p0 + p1 + p2 + p3;
      float c3 = p0 - p1 + p2 - p3;              // i bit3 (= nt bit0)
      float c4 = p0 + p1 - p2 - p3;              // i bit4 (= nt bit1)
      #pragma unroll
      for (int m = 1; m <= 8; m <<= 1) {
        float o = __shfl_xor(ca, m, 64);
        ca = (lane & m) ? (o - ca) : (ca + o);   // WHT stage
        c3 += __shfl_xor(c3, m, 64);             // plain sum
        c4 += __shfl_xor(c4, m, 64);
      }
      int rloc = mt * 16 + quad * 4 + r;
      if (cn == 0) {
        zb[5 * 64 + rloc] = ca;                  // W_0: unsigned sum
        zb[3 * 64 + rloc] = c3;
        zb[4 * 64 + rloc] = c4;
      } else if (cn == 2) {
        zb[0 * 64 + rloc] = ca;                  // W_2: i bit0
      } else if (cn == 4) {
        zb[1 * 64 + rloc] = ca;                  // W_4: i bit1
      } else if (cn == 8) {
        zb[2 * 64 + rloc] = ca;                  // W_8: i bit2
      }
    }
  }
}

// -------------------------------------------------------------- finalize ---
__global__ __launch_bounds__(256) void finalize(const float* __restrict__ Zp,
                                                const float* __restrict__ W,
                                                const float* __restrict__ bias,
                                                float* __restrict__ out) {
  int rg = blockIdx.x * 256 + threadIdx.x;      // 0..4095
  int mtile = rg >> 7;
  int rl = rg & 127;
  int wlo = rl >> 6;                            // wave low bit (wm)
  int rloc = rl & 63;
  float z[10];
  #pragma unroll
  for (int q = 0; q < 10; ++q) z[q] = 0.f;
  for (int ntile = 0; ntile < 16; ++ntile) {
    int bid = ntile * 32 + mtile;
    #pragma unroll
    for (int wn = 0; wn < 2; ++wn) {
      int w = (wn << 1) | wlo;
      const float* P = Zp + (size_t)(bid * 4 + w) * 6 * 64 + rloc;
      z[9] += P[0];
      z[8] += P[64];
      z[7] += P[128];
      z[6] += P[192];
      z[5] += P[256];
      float pa = P[320];
      z[4] += wn ? -pa : pa;                    // i bit5
      z[3] += (ntile & 1) ? -pa : pa;           // bit6
      z[2] += (ntile & 2) ? -pa : pa;           // bit7
      z[1] += (ntile & 4) ? -pa : pa;           // bit8
      z[0] += (ntile & 8) ? -pa : pa;           // bit9
    }
  }
  #pragma unroll
  for (int o = 0; o < NOUT; ++o) {
    float a = bias[o];
    #pragma unroll
    for (int q = 0; q < 10; ++q) a += z[q] * W[o * 10 + q];
    out[(size_t)rg * NOUT + o] = a;
  }
}

extern "C" void kernel_launch(void* const* d_in, const int* in_sizes, int n_in,
                              void* d_out, int out_size, void* d_ws, size_t ws_size,
                              hipStream_t stream) {
  const float* X    = (const float*)d_in[0];
  const float* wts  = (const float*)d_in[1];
  const float* W    = (const float*)d_in[2];
  const float* bias = (const float*)d_in[3];
  float* out = (float*)d_out;
  char* ws = (char*)d_ws;
  unsigned short* Xn = (unsigned short*)ws;                       // 8 MB
  unsigned short* Ub = (unsigned short*)(ws + 8u  * 1024 * 1024); // 4 MB
  unsigned int* Ut   = (unsigned int*)(ws + 12u * 1024 * 1024);   // 4 MB
  float* Zp          = (float*)(ws + 16u * 1024 * 1024);          // 3 MB

  hipLaunchKernelGGL(build_u,        dim3(DIMQ / 2),  dim3(256), 0, stream, wts, Ut);
  hipLaunchKernelGGL(normalize_rows, dim3(BATCH / 4), dim3(256), 0, stream, X, Xn);
  hipLaunchKernelGGL(transpose_u,    dim3(256),       dim3(256), 0, stream, Ut, Ub);
  hipLaunchKernelGGL(gemm_bt,        dim3((GM/128)*(GN/128)), dim3(256), 0, stream, Xn, Ub, Zp);
  hipLaunchKernelGGL(finalize,       dim3(BATCH / 256), dim3(256), 0, stream, Zp, W, bias, out);
}